// Round 8
// baseline (225.522 us; speedup 1.0000x reference)
//
#include <hip/hip_runtime.h>
#include <math.h>

#define N_    8
#define C_    256
#define H_    64
#define W_    64
#define HW    4096
#define OUT_  256
#define HEADS 8
#define HD    32
#define K2    9
#define OFFCH 144   // HEADS*K2*2
#define AWCH  72    // HEADS*K2
#define COP   224   // padded conv output channels (216 used)
#define KTOT  2304  // 9 taps * 256 c

typedef __bf16 bf16x8 __attribute__((ext_vector_type(8)));
typedef __bf16 bf16x4 __attribute__((ext_vector_type(4)));
typedef float  f32x4  __attribute__((ext_vector_type(4)));

// ---------------------------------------------------------------------------
// pack_x: fp32 NCHW -> bf16 NHWC  (xp[n][y][x][c]), LDS 64x64 tile transpose.
// ---------------------------------------------------------------------------
__global__ __launch_bounds__(256) void pack_x_kernel(
    const float* __restrict__ x, __bf16* __restrict__ xp)
{
  const int c0 = blockIdx.x << 6;
  const int y  = blockIdx.y;
  const int n  = blockIdx.z;
  const int tid = threadIdx.x;
  __shared__ float tile[64][65];

  const int tx = tid & 63, tg = tid >> 6;
#pragma unroll
  for (int i = 0; i < 16; ++i) {
    int cl = tg + (i << 2);
    tile[cl][tx] = x[((size_t)(n * C_ + c0 + cl) * H_ + y) * W_ + tx];
  }
  __syncthreads();
#pragma unroll
  for (int i = 0; i < 16; ++i) {
    int xl = tg + (i << 2);
    xp[((size_t)(n * HW) + y * W_ + xl) * C_ + c0 + tx] = (__bf16)tile[tx][xl];
  }
}

// ---------------------------------------------------------------------------
// pack_w: conv weights -> bf16 Wp[224][tap][c] (tap-major K), + bias pack.
// ---------------------------------------------------------------------------
__global__ __launch_bounds__(256) void pack_w_kernel(
    const float* __restrict__ off_w, const float* __restrict__ off_b,
    const float* __restrict__ attn_w, const float* __restrict__ attn_b,
    __bf16* __restrict__ Wp, float* __restrict__ biasp)
{
  const int co = blockIdx.x;
  const int c  = threadIdx.x;
  const float* base = nullptr;
  if (co < OFFCH)      base = off_w  + ((size_t)co * C_ + c) * 9;
  else if (co < 216)   base = attn_w + ((size_t)(co - OFFCH) * C_ + c) * 9;
#pragma unroll
  for (int t = 0; t < 9; ++t) {
    float w = base ? base[t] : 0.f;
    Wp[(size_t)co * KTOT + t * C_ + c] = (__bf16)w;
  }
  if (c == 0) {
    float b = 0.f;
    if (co < OFFCH) b = off_b[co];
    else if (co < 216) b = attn_b[co - OFFCH];
    biasp[co] = b;
  }
}

// 256x256 fp32 -> bf16 row-major
__global__ __launch_bounds__(256) void pack_mat_kernel(
    const float* __restrict__ Wsrc, __bf16* __restrict__ Wdst)
{
  const int i = blockIdx.x * 256 + threadIdx.x;
  Wdst[i] = (__bf16)Wsrc[i];
}

// ---------------------------------------------------------------------------
// conv_mfma: implicit-GEMM 3x3 conv via 16x16x32 bf16 MFMA.
// Restructured: B staged per 3-tap group (7 barriers/c-slice, was 18);
// reg-staged split staging hides L2 latency under MFMA clusters;
// chunk-XOR (row&3) LDS swizzle on A and B; setprio around MFMA.
// Block: 128 spatial (2 image rows) x 112 co; 4 waves = 2 rows x 2 x-halves.
// ---------------------------------------------------------------------------
__global__ __launch_bounds__(256) void conv_mfma_kernel(
    const __bf16* __restrict__ xp, const __bf16* __restrict__ Wp,
    const float* __restrict__ biasp, __bf16* __restrict__ P)
{
  const int st = blockIdx.x;
  const int bn = blockIdx.y;
  const int n  = blockIdx.z;
  const int y0 = st << 1;
  const int tid = threadIdx.x;

  __shared__ __align__(16) __bf16 Asl[4][66][40];   // 21.1 KB
  __shared__ __align__(16) __bf16 Bsl[3][112][40];  // 26.9 KB  (one 3-tap group)

  const int lw = tid & 63, wv = tid >> 6;
  const int trow = wv >> 1;           // wave's image row (0/1)
  const int xb   = (wv & 1) << 5;     // wave's x base (0/32)
  const int lr = lw & 15, lg = lw >> 4;

  f32x4 acc[2][7];
#pragma unroll
  for (int m = 0; m < 2; ++m)
#pragma unroll
    for (int nt = 0; nt < 7; ++nt) acc[m][nt] = (f32x4){0.f, 0.f, 0.f, 0.f};

  uint4 areg[4];
  uint4 breg[6];

  // ---- staging helpers (reg-staged; XOR chunk swizzle on LDS writes) ----
  auto load_A = [&](int c0) {
#pragma unroll
    for (int it = 0; it < 4; ++it) {
      int i = tid + (it << 8);
      int cg = i & 3, xx = (i >> 2) & 63, r = i >> 8;
      int y = y0 - 1 + r;
      uint4 v = make_uint4(0u, 0u, 0u, 0u);
      if ((unsigned)y < (unsigned)H_)
        v = *(const uint4*)&xp[(((size_t)n * HW) + y * W_ + xx) * C_ + c0 + (cg << 3)];
      areg[it] = v;
    }
  };
  auto write_A = [&]() {
#pragma unroll
    for (int it = 0; it < 4; ++it) {
      int i = tid + (it << 8);
      int cg = i & 3, xx = (i >> 2) & 63, r = i >> 8;
      int row = xx + 1;
      *(uint4*)&Asl[r][row][(cg ^ (row & 3)) << 3] = areg[it];
    }
  };
  auto load_B = [&](int g, int c0) {
#pragma unroll
    for (int it = 0; it < 6; ++it) {
      const int tt = it >> 1;
      int sub = ((it & 1) << 8) + tid;   // 0..511
      int co  = sub >> 2, cg = sub & 3;
      if (co < 112)
        breg[it] = *(const uint4*)&Wp[(size_t)(bn * 112 + co) * KTOT +
                                      (g * 3 + tt) * C_ + c0 + (cg << 3)];
    }
  };
  auto write_B = [&]() {
#pragma unroll
    for (int it = 0; it < 6; ++it) {
      const int tt = it >> 1;
      int sub = ((it & 1) << 8) + tid;
      int co  = sub >> 2, cg = sub & 3;
      if (co < 112)
        *(uint4*)&Bsl[tt][co][(cg ^ (co & 3)) << 3] = breg[it];
    }
  };
  auto mfma3 = [&](int g) {
#pragma unroll
    for (int tt = 0; tt < 3; ++tt) {
      const int r   = trow + g;           // trow + (g-1) + 1
      const int xc0 = xb + lr + tt;       // xb + lr + (tt-1) + 1
      const int xc1 = xc0 + 16;
      bf16x8 a0 = *(const bf16x8*)&Asl[r][xc0][(lg ^ (xc0 & 3)) << 3];
      bf16x8 a1 = *(const bf16x8*)&Asl[r][xc1][(lg ^ (xc1 & 3)) << 3];
#pragma unroll
      for (int nt = 0; nt < 7; ++nt) {
        const int row = (nt << 4) + lr;
        bf16x8 b = *(const bf16x8*)&Bsl[tt][row][(lg ^ (row & 3)) << 3];
        acc[0][nt] = __builtin_amdgcn_mfma_f32_16x16x32_bf16(a0, b, acc[0][nt], 0, 0, 0);
        acc[1][nt] = __builtin_amdgcn_mfma_f32_16x16x32_bf16(a1, b, acc[1][nt], 0, 0, 0);
      }
    }
  };

  // ---- prologue: zero halo columns once; prefetch A(0), B(g0,0) ----
  if (tid < 32) {
    int r = tid >> 3, xe = ((tid >> 2) & 1) ? 65 : 0, cg = tid & 3;
    *(uint4*)&Asl[r][xe][cg << 3] = make_uint4(0u, 0u, 0u, 0u);
  }
  load_A(0);
  load_B(0, 0);

  for (int ci = 0; ci < 8; ++ci) {
    const int c0 = ci << 5;
    __syncthreads();                       // prev g2 reads + prev A reads done
    write_A();
    write_B();                             // B group 0
    load_B(1, c0);                         // in flight under mfma3(0)
    __syncthreads();                       // A + B0 ready
    __builtin_amdgcn_s_setprio(1); mfma3(0); __builtin_amdgcn_s_setprio(0);
    __syncthreads();                       // B0 reads done
    write_B();                             // B group 1
    load_B(2, c0);
    __syncthreads();
    __builtin_amdgcn_s_setprio(1); mfma3(1); __builtin_amdgcn_s_setprio(0);
    __syncthreads();
    write_B();                             // B group 2
    if (ci < 7) { load_A(c0 + 32); load_B(0, c0 + 32); }
    __syncthreads();
    __builtin_amdgcn_s_setprio(1); mfma3(2); __builtin_amdgcn_s_setprio(0);
  }

  // ---- epilogue: bias (+ sigmoid for co>=144), store bf16 P[n][s][co] ----
  const int yout = y0 + trow;
#pragma unroll
  for (int m = 0; m < 2; ++m) {
#pragma unroll
    for (int nt = 0; nt < 7; ++nt) {
      const int co = bn * 112 + (nt << 4) + lr;
      const float bias = biasp[co];
#pragma unroll
      for (int reg = 0; reg < 4; ++reg) {
        const int xo = xb + (m << 4) + (lg << 2) + reg;
        float v = acc[m][nt][reg] + bias;
        if (co >= OFFCH) v = 1.f / (1.f + expf(-v));
        P[((size_t)n * HW + yout * W_ + xo) * COP + co] = (__bf16)v;
      }
    }
  }
}

// ---------------------------------------------------------------------------
// gemm256: D[n][s][co] = sum_c A[n][s][c]*Wb[co][c]
// MODE 0: store bf16 NHWC (vproj -> vtb). MODE 1: store fp32 NCHW (wo -> out).
// ---------------------------------------------------------------------------
template <int MODE>
__global__ __launch_bounds__(256) void gemm256_kernel(
    const __bf16* __restrict__ A, const __bf16* __restrict__ Wb,
    __bf16* __restrict__ out_b, float* __restrict__ out_f)
{
  const int st = blockIdx.x;
  const int bn = blockIdx.y;
  const int n  = blockIdx.z;
  const int s0 = st << 7;
  const int tid = threadIdx.x;

  __shared__ __bf16 Asl[128][40];
  __shared__ __bf16 Bsl[128][40];

  const int lw = tid & 63, wv = tid >> 6;
  const int lr = lw & 15, lg = lw >> 4;
  const int sm_base = wv << 5;

  f32x4 acc[2][8];
#pragma unroll
  for (int m = 0; m < 2; ++m)
#pragma unroll
    for (int nt = 0; nt < 8; ++nt) acc[m][nt] = (f32x4){0.f, 0.f, 0.f, 0.f};

  for (int c0 = 0; c0 < 256; c0 += 32) {
    __syncthreads();
#pragma unroll
    for (int it = 0; it < 2; ++it) {
      int i = tid + (it << 8);
      int cg = i & 3, r = i >> 2;
      *(uint4*)&Asl[r][cg << 3] =
          *(const uint4*)&A[((size_t)n * HW + s0 + r) * 256 + c0 + (cg << 3)];
    }
#pragma unroll
    for (int it = 0; it < 2; ++it) {
      int i = tid + (it << 8);
      int cg = i & 3, r = i >> 2;
      *(uint4*)&Bsl[r][cg << 3] =
          *(const uint4*)&Wb[(size_t)((bn << 7) + r) * 256 + c0 + (cg << 3)];
    }
    __syncthreads();

    bf16x8 a0 = *(const bf16x8*)&Asl[sm_base + lr][lg << 3];
    bf16x8 a1 = *(const bf16x8*)&Asl[sm_base + 16 + lr][lg << 3];
#pragma unroll
    for (int nt = 0; nt < 8; ++nt) {
      bf16x8 b = *(const bf16x8*)&Bsl[(nt << 4) + lr][lg << 3];
      acc[0][nt] = __builtin_amdgcn_mfma_f32_16x16x32_bf16(a0, b, acc[0][nt], 0, 0, 0);
      acc[1][nt] = __builtin_amdgcn_mfma_f32_16x16x32_bf16(a1, b, acc[1][nt], 0, 0, 0);
    }
  }

#pragma unroll
  for (int m = 0; m < 2; ++m) {
#pragma unroll
    for (int nt = 0; nt < 8; ++nt) {
      const int co = (bn << 7) + (nt << 4) + lr;
      if (MODE == 0) {
#pragma unroll
        for (int reg = 0; reg < 4; ++reg) {
          const int sm = sm_base + (m << 4) + (lg << 2) + reg;
          out_b[((size_t)n * HW + s0 + sm) * 256 + co] = (__bf16)acc[m][nt][reg];
        }
      } else {
        const int sm = sm_base + (m << 4) + (lg << 2);
        float4 v4 = make_float4(acc[m][nt][0], acc[m][nt][1],
                                acc[m][nt][2], acc[m][nt][3]);
        *(float4*)&out_f[((size_t)(n * 256 + co)) * HW + s0 + sm] = v4;
      }
    }
  }
}

// ---------------------------------------------------------------------------
// Deformable sampling, channel-split: 8 lanes per (n,h,s), each owns 4 ch.
// ---------------------------------------------------------------------------
__global__ __launch_bounds__(256) void sample_kernel(
    const __bf16* __restrict__ vtb, const __bf16* __restrict__ P,
    __bf16* __restrict__ comb)
{
  const int gid = blockIdx.x * 256 + threadIdx.x;
  const int cg  = gid & 7;
  const int q   = gid >> 3;
  const int s = q & (HW - 1);
  const int h = (q >> 12) & (HEADS - 1);
  const int n = q >> 15;
  const int yq = s >> 6, xq = s & 63;

  float a0 = 0.f, a1 = 0.f, a2 = 0.f, a3 = 0.f;

  const __bf16* prow  = P + ((size_t)n * HW + s) * COP;
  const __bf16* vbase = vtb + ((size_t)n * HW) * OUT_ + h * HD + (cg << 2);

#pragma unroll
  for (int k = 0; k < K2; ++k) {
    const float offx = (float)prow[18 * h + 2 * k];
    const float offy = (float)prow[18 * h + 2 * k + 1];
    const float a    = (float)prow[OFFCH + 9 * h + k];

    const float xpf = (float)xq + offx * (63.f / 64.f);
    const float ypf = (float)yq + offy * (63.f / 64.f);
    const float fx0 = floorf(xpf), fy0 = floorf(ypf);
    const int x0 = (int)fx0, y0 = (int)fy0;
    const float wx1 = xpf - fx0, wx0 = 1.f - wx1;
    const float wy1 = ypf - fy0, wy0 = 1.f - wy1;

#pragma unroll
    for (int cy = 0; cy < 2; ++cy) {
      const int yi = y0 + cy;
      if ((unsigned)yi >= (unsigned)H_) continue;
      const float wy = cy ? wy1 : wy0;
#pragma unroll
      for (int cx = 0; cx < 2; ++cx) {
        const int xi = x0 + cx;
        if ((unsigned)xi >= (unsigned)W_) continue;
        const float cw = a * wy * (cx ? wx1 : wx0);
        bf16x4 v = *(const bf16x4*)(vbase + (size_t)(yi * W_ + xi) * OUT_);
        a0 = fmaf(cw, (float)v[0], a0);
        a1 = fmaf(cw, (float)v[1], a1);
        a2 = fmaf(cw, (float)v[2], a2);
        a3 = fmaf(cw, (float)v[3], a3);
      }
    }
  }

  bf16x4 r;
  r[0] = (__bf16)a0; r[1] = (__bf16)a1; r[2] = (__bf16)a2; r[3] = (__bf16)a3;
  *(bf16x4*)&comb[((size_t)n * HW + s) * OUT_ + h * HD + (cg << 2)] = r;
}

// ---------------------------------------------------------------------------
extern "C" void kernel_launch(void* const* d_in, const int* in_sizes, int n_in,
                              void* d_out, int out_size, void* d_ws,
                              size_t ws_size, hipStream_t stream)
{
  const float* x      = (const float*)d_in[0];
  // d_in[1] = Wq, d_in[2] = Wk : dead code (q,k unused in reference)
  const float* Wv     = (const float*)d_in[3];
  const float* off_w  = (const float*)d_in[4];
  const float* off_b  = (const float*)d_in[5];
  const float* attn_w = (const float*)d_in[6];
  const float* attn_b = (const float*)d_in[7];
  const float* Wo     = (const float*)d_in[8];
  float* out = (float*)d_out;

  __bf16* vtb   = (__bf16*)d_ws;                         // 16.78 MB
  __bf16* xp    = vtb + (size_t)N_ * HW * OUT_;          // 16.78 MB
  __bf16* comb  = xp + (size_t)N_ * HW * C_;             // 16.78 MB
  __bf16* P     = comb + (size_t)N_ * HW * OUT_;         // 14.68 MB
  __bf16* Wp    = P + (size_t)N_ * HW * COP;             //  1.03 MB
  __bf16* Wvb   = Wp + (size_t)COP * KTOT;               //  128 KB
  __bf16* Wob   = Wvb + (size_t)OUT_ * C_;               //  128 KB
  float*  biasp = (float*)(Wob + (size_t)OUT_ * OUT_);   //  896 B

  pack_w_kernel<<<dim3(COP), 256, 0, stream>>>(off_w, off_b, attn_w, attn_b,
                                               Wp, biasp);
  pack_mat_kernel<<<dim3(256), 256, 0, stream>>>(Wv, Wvb);
  pack_mat_kernel<<<dim3(256), 256, 0, stream>>>(Wo, Wob);
  pack_x_kernel<<<dim3(4, 64, N_), 256, 0, stream>>>(x, xp);
  conv_mfma_kernel<<<dim3(32, 2, N_), 256, 0, stream>>>(xp, Wp, biasp, P);
  gemm256_kernel<0><<<dim3(32, 2, N_), 256, 0, stream>>>(xp, Wvb, vtb, nullptr);
  sample_kernel<<<dim3((N_ * HEADS * HW * 8) / 256), 256, 0, stream>>>(vtb, P,
                                                                       comb);
  gemm256_kernel<1><<<dim3(32, 2, N_), 256, 0, stream>>>(comb, Wob, nullptr,
                                                         out);
}